// Round 9
// baseline (253.308 us; speedup 1.0000x reference)
//
#include <hip/hip_runtime.h>
#include <math.h>

#define S_LEN 512
#define BATCH 256
#define NTAG  128
#define EMSTRIDE (BATCH * NTAG)  /* floats per time step */

typedef float    f32x2 __attribute__((ext_vector_type(2)));
typedef float    f32x4 __attribute__((ext_vector_type(4)));
typedef int      i32x4 __attribute__((ext_vector_type(4)));
typedef _Float16 h16x2 __attribute__((ext_vector_type(2)));

#define DPP_XOR1(x) __int_as_float(__builtin_amdgcn_mov_dpp(__float_as_int(x), 0xB1, 0xF, 0xF, false))
#define DPP_XOR2(x) __int_as_float(__builtin_amdgcn_mov_dpp(__float_as_int(x), 0x4E, 0xF, 0xF, false))

__device__ __forceinline__ int pkmax(int a, int b) {
  int r; asm("v_pk_max_f16 %0, %1, %2" : "=v"(r) : "v"(a), "v"(b)); return r;
}
__device__ __forceinline__ int pkmul(int a, int b) {
  int r; asm("v_pk_mul_f16 %0, %1, %2" : "=v"(r) : "v"(a), "v"(b)); return r;
}
__device__ __forceinline__ float dot2(int e, int w, float c) {
  return __builtin_amdgcn_fdot2(__builtin_bit_cast(h16x2, e),
                                __builtin_bit_cast(h16x2, w), c, false);
}
__device__ __forceinline__ int packh(float a, float b) {
  return __builtin_bit_cast(int, __builtin_amdgcn_cvt_pkrtz(a, b));
}
__device__ __forceinline__ f32x2 unpackh(int p) {
  h16x2 h = __builtin_bit_cast(h16x2, p);
  f32x2 r; r[0] = (float)h[0]; r[1] = (float)h[1]; return r;
}
__device__ __forceinline__ int emidx(bool isR, int len, int i) {
  int s = isR ? (len - 2 - i) : (1 + i);
  return s < 0 ? 0 : (s > S_LEN - 1 ? S_LEN - 1 : s);
}

// ---------------------------------------------------------------------------
// Chain kernel: grid 2*BATCH, 256 threads.
//   blk <  BATCH: chain block for batch b=blk. Wave w (tid>>6) = role:
//     0=fwd-left, 1=fwd-right, 2=vit-left, 3=vit-right (meet at sm=(len-1)>>1).
//   blk >= BATCH: gold-path block for b=blk-BATCH.
// Each chain is ONE wave: lane l owns output rows 2l,2l+1 (E rows as f16
// pairs in 128 VGPRs); state = 64 f16-pairs in LDS, read via uniform
// broadcast ds_read_b128 by all lanes -> renorm max computed redundantly
// per-lane, NO cross-lane ops, NO barriers (single-wave ordering + lgkmcnt).
// Forward: v_dot2_f32_f16. Viterbi in exp space: pk_mul + pk_max (max
// commutes with positive scaling). Per-step power-of-2 renorm, exponent in Ew.
// ---------------------------------------------------------------------------
__global__ __launch_bounds__(256, 1)
void crf_chain_kernel(const float* __restrict__ emis,
                      const float* __restrict__ mask,
                      const int* __restrict__ tags,
                      const float* __restrict__ trans,
                      const float* __restrict__ startt,
                      const float* __restrict__ stopt,
                      float* __restrict__ ws,
                      int* __restrict__ ewbuf,
                      float* __restrict__ out)
{
  const int blk = blockIdx.x;
  const int tid = threadIdx.x;

  __shared__ __align__(16) int cbuf[4][2][64];
  __shared__ float red[16];

  // ---------------- gold role (256-thread block, 2 steps/thread) ----------
  if (blk >= BATCH) {
    const int b = blk - BATCH;
    float part = 0.f, lenp = 0.f;
#pragma unroll
    for (int rep = 0; rep < 2; ++rep) {
      int s = tid + rep * 256;
      float m  = mask[(size_t)s * BATCH + b];
      int  cur = tags[(size_t)s * BATCH + b];
      if (s == 0) {
        part += startt[cur] + emis[(size_t)b * NTAG + cur] * m;
      } else {
        int prev = tags[(size_t)(s - 1) * BATCH + b];
        part += m * (trans[(size_t)prev * NTAG + cur] +
                     emis[((size_t)s * BATCH + b) * NTAG + cur]);
      }
      lenp += m;
    }
#pragma unroll
    for (int d = 1; d <= 32; d <<= 1) {
      part += __shfl_xor(part, d);
      lenp += __shfl_xor(lenp, d);
    }
    const int lane = tid & 63, wid = tid >> 6;
    if (lane == 0) { red[wid] = part; red[8 + wid] = lenp; }
    __syncthreads();
    if (tid == 0) {
      float rps = (red[0] + red[1]) + (red[2] + red[3]);
      float lf  = (red[8] + red[9]) + (red[10] + red[11]);
      int len = (int)(lf + 0.5f);
      int pf  = tags[(size_t)(len - 1) * BATCH + b];
      out[1 + b] = rps + stopt[pf];
    }
    return;
  }

  const int  b    = blk;
  const int  role = tid >> 6;   // wave id == role, uniform per wave
  const int  l    = tid & 63;
  const bool isR  = (role & 1) != 0;
  const bool isV  = (role >= 2);

  // ---- len = sum_s mask[s,b] (mask monotone), per-wave butterfly ----
  float mv = 0.f;
#pragma unroll
  for (int r = 0; r < 8; ++r) mv += mask[(size_t)(l + 64 * r) * BATCH + b];
#pragma unroll
  for (int d = 1; d <= 32; d <<= 1) mv += __shfl_xor(mv, d);
  const int len = (int)(mv + 0.5f);

  const int sm  = (len - 1) >> 1;
  const int nst = len - 1 - sm;
  const int cnt = isR ? nst : sm;

  // ---- E = exp(trans) as f16 pairs; lane l holds rows 2l, 2l+1 ----
  // left: out[j] = sum/max_k M[j,k]*state[k], M[j,k] = exp(trans[j][k])
  // right: M[j,k] = exp(trans[k][j])  (transposed)
  int EA[64], EB[64];
  if (!isR) {
    const f32x4* r0 = (const f32x4*)(trans + (size_t)(2 * l) * NTAG);
    const f32x4* r1 = (const f32x4*)(trans + (size_t)(2 * l + 1) * NTAG);
#pragma unroll
    for (int mm = 0; mm < 32; ++mm) {
      f32x4 x0 = r0[mm], x1 = r1[mm];
      EA[2 * mm]     = packh(__expf(x0[0]), __expf(x0[1]));
      EA[2 * mm + 1] = packh(__expf(x0[2]), __expf(x0[3]));
      EB[2 * mm]     = packh(__expf(x1[0]), __expf(x1[1]));
      EB[2 * mm + 1] = packh(__expf(x1[2]), __expf(x1[3]));
    }
  } else {
#pragma unroll
    for (int m = 0; m < 64; ++m) {
      f32x2 p0 = *(const f32x2*)(trans + (size_t)(2 * m) * NTAG + 2 * l);
      f32x2 p1 = *(const f32x2*)(trans + (size_t)(2 * m + 1) * NTAG + 2 * l);
      EA[m] = packh(__expf(p0[0]), __expf(p1[0]));
      EB[m] = packh(__expf(p0[1]), __expf(p1[1]));
    }
  }

  // ---- init state (normalized to max ~ 2^0) ----
  const float* ebm = emis + (size_t)b * NTAG + 2 * l;
  float iA, iB;
  if (!isR) {
    iA = startt[2 * l]     + ebm[0];
    iB = startt[2 * l + 1] + ebm[1];
  } else {
    float eA = 0.f, eB = 0.f;
    if (nst > 0) {
      f32x2 e = *(const f32x2*)(ebm + (size_t)(len - 1) * EMSTRIDE);
      eA = e[0]; eB = e[1];
    }
    iA = stopt[2 * l]     + eA;
    iB = stopt[2 * l + 1] + eB;
  }
  float uA = __expf(iA), uB = __expf(iB);
  float mx0 = fmaxf(uA, uB);
  mx0 = fmaxf(mx0, DPP_XOR1(mx0));
  mx0 = fmaxf(mx0, DPP_XOR2(mx0));
  mx0 = fmaxf(mx0, __shfl_xor(mx0, 4));
  mx0 = fmaxf(mx0, __shfl_xor(mx0, 8));
  mx0 = fmaxf(mx0, __shfl_xor(mx0, 16));
  mx0 = fmaxf(mx0, __shfl_xor(mx0, 32));
  unsigned eb0 = (__float_as_uint(mx0) >> 23) & 0xFF;
  int Ew = (int)eb0 - 127;
  float sc0 = __uint_as_float((unsigned)(254 - eb0) << 23);  // 2^-e
  cbuf[role][0][l] = packh(uA * sc0, uB * sc0);
  asm volatile("s_waitcnt lgkmcnt(0)" ::: "memory");

  // ---- emission prefetch (pair per step per lane), depth 4 ----
  f32x2 e0 = *(const f32x2*)(ebm + (size_t)emidx(isR, len, 0) * EMSTRIDE);
  f32x2 e1 = *(const f32x2*)(ebm + (size_t)emidx(isR, len, 1) * EMSTRIDE);
  f32x2 e2 = *(const f32x2*)(ebm + (size_t)emidx(isR, len, 2) * EMSTRIDE);
  f32x2 e3 = *(const f32x2*)(ebm + (size_t)emidx(isR, len, 3) * EMSTRIDE);

  int fin = cnt & 1;

#define TMAX(QQ) pkmax(pkmax(QQ[0], QQ[1]), pkmax(QQ[2], QQ[3]))

#define DQ(QQ, MB)                                                            \
      a0 = dot2(EA[(MB)+0], QQ[0], a0); b0 = dot2(EB[(MB)+0], QQ[0], b0);     \
      a1 = dot2(EA[(MB)+1], QQ[1], a1); b1 = dot2(EB[(MB)+1], QQ[1], b1);     \
      a2 = dot2(EA[(MB)+2], QQ[2], a2); b2 = dot2(EB[(MB)+2], QQ[2], b2);     \
      a3 = dot2(EA[(MB)+3], QQ[3], a3); b3 = dot2(EB[(MB)+3], QQ[3], b3);

#define VQ(QQ, MB)                                                            \
      pA0 = pkmax(pA0, pkmul(EA[(MB)+0], QQ[0]));                             \
      pB0 = pkmax(pB0, pkmul(EB[(MB)+0], QQ[0]));                             \
      pA1 = pkmax(pA1, pkmul(EA[(MB)+1], QQ[1]));                             \
      pB1 = pkmax(pB1, pkmul(EB[(MB)+1], QQ[1]));                             \
      pA2 = pkmax(pA2, pkmul(EA[(MB)+2], QQ[2]));                             \
      pB2 = pkmax(pB2, pkmul(EB[(MB)+2], QQ[2]));                             \
      pA3 = pkmax(pA3, pkmul(EA[(MB)+3], QQ[3]));                             \
      pB3 = pkmax(pB3, pkmul(EB[(MB)+3], QQ[3]));

#define STEP(U, EV)                                                           \
  {                                                                           \
    const int i_ = gb + (U);                                                  \
    if (i_ >= cnt) goto epi;                                                  \
    const i32x4* rp_ = (const i32x4*)cbuf[role][(U) & 1];                     \
    i32x4 Q0 = rp_[0],  Q1 = rp_[1],  Q2 = rp_[2],  Q3 = rp_[3];              \
    i32x4 Q4 = rp_[4],  Q5 = rp_[5],  Q6 = rp_[6],  Q7 = rp_[7];              \
    i32x4 Q8 = rp_[8],  Q9 = rp_[9],  Q10 = rp_[10], Q11 = rp_[11];           \
    i32x4 Q12 = rp_[12], Q13 = rp_[13], Q14 = rp_[14], Q15 = rp_[15];         \
    int t0 = TMAX(Q0),  t1 = TMAX(Q1),  t2 = TMAX(Q2),  t3 = TMAX(Q3);        \
    int t4 = TMAX(Q4),  t5 = TMAX(Q5),  t6 = TMAX(Q6),  t7 = TMAX(Q7);        \
    int t8 = TMAX(Q8),  t9 = TMAX(Q9),  t10 = TMAX(Q10), t11 = TMAX(Q11);     \
    int t12 = TMAX(Q12), t13 = TMAX(Q13), t14 = TMAX(Q14), t15 = TMAX(Q15);   \
    t0 = pkmax(t0, t1);   t2 = pkmax(t2, t3);                                 \
    t4 = pkmax(t4, t5);   t6 = pkmax(t6, t7);                                 \
    t8 = pkmax(t8, t9);   t10 = pkmax(t10, t11);                              \
    t12 = pkmax(t12, t13); t14 = pkmax(t14, t15);                             \
    t0 = pkmax(t0, t2); t4 = pkmax(t4, t6);                                   \
    t8 = pkmax(t8, t10); t12 = pkmax(t12, t14);                               \
    t0 = pkmax(t0, t4); t8 = pkmax(t8, t12); t0 = pkmax(t0, t8);              \
    f32x2 mh_ = unpackh(t0);                                                  \
    float mxx_ = fmaxf(mh_[0], mh_[1]);                                       \
    unsigned ebx_ = (__float_as_uint(mxx_) >> 23) & 0xFF;                     \
    float sc_ = __uint_as_float((unsigned)((isV ? 242u : 246u) - ebx_) << 23);\
    Ew += (int)ebx_ - 127 + (isV ? 12 : 8);                                   \
    const bool lastR_ = isR && (i_ == cnt - 1);                               \
    float exA_ = lastR_ ? 1.f : __expf((EV)[0]);                              \
    float exB_ = lastR_ ? 1.f : __expf((EV)[1]);                              \
    float vA_, vB_;                                                           \
    if (!isV) {                                                               \
      float a0 = 0.f, a1 = 0.f, a2 = 0.f, a3 = 0.f;                           \
      float b0 = 0.f, b1 = 0.f, b2 = 0.f, b3 = 0.f;                           \
      DQ(Q0, 0)  DQ(Q1, 4)  DQ(Q2, 8)   DQ(Q3, 12)                            \
      DQ(Q4, 16) DQ(Q5, 20) DQ(Q6, 24)  DQ(Q7, 28)                            \
      DQ(Q8, 32) DQ(Q9, 36) DQ(Q10, 40) DQ(Q11, 44)                           \
      DQ(Q12, 48) DQ(Q13, 52) DQ(Q14, 56) DQ(Q15, 60)                         \
      vA_ = (a0 + a1) + (a2 + a3);                                            \
      vB_ = (b0 + b1) + (b2 + b3);                                            \
    } else {                                                                  \
      int pA0 = 0, pA1 = 0, pA2 = 0, pA3 = 0;                                 \
      int pB0 = 0, pB1 = 0, pB2 = 0, pB3 = 0;                                 \
      VQ(Q0, 0)  VQ(Q1, 4)  VQ(Q2, 8)   VQ(Q3, 12)                            \
      VQ(Q4, 16) VQ(Q5, 20) VQ(Q6, 24)  VQ(Q7, 28)                            \
      VQ(Q8, 32) VQ(Q9, 36) VQ(Q10, 40) VQ(Q11, 44)                           \
      VQ(Q12, 48) VQ(Q13, 52) VQ(Q14, 56) VQ(Q15, 60)                         \
      int pA_ = pkmax(pkmax(pA0, pA1), pkmax(pA2, pA3));                      \
      int pB_ = pkmax(pkmax(pB0, pB1), pkmax(pB2, pB3));                      \
      f32x2 ua_ = unpackh(pA_), ub_ = unpackh(pB_);                           \
      vA_ = fmaxf(ua_[0], ua_[1]);                                            \
      vB_ = fmaxf(ub_[0], ub_[1]);                                            \
    }                                                                         \
    cbuf[role][((U) + 1) & 1][l] = packh(exA_ * vA_ * sc_, exB_ * vB_ * sc_); \
    asm volatile("s_waitcnt lgkmcnt(0)" ::: "memory");                        \
  }

  for (int gb = 0; gb < 256; gb += 4) {
    f32x2 n0 = *(const f32x2*)(ebm + (size_t)emidx(isR, len, gb + 4) * EMSTRIDE);
    f32x2 n1 = *(const f32x2*)(ebm + (size_t)emidx(isR, len, gb + 5) * EMSTRIDE);
    f32x2 n2 = *(const f32x2*)(ebm + (size_t)emidx(isR, len, gb + 6) * EMSTRIDE);
    f32x2 n3 = *(const f32x2*)(ebm + (size_t)emidx(isR, len, gb + 7) * EMSTRIDE);
    STEP(0, e0)
    STEP(1, e1)
    STEP(2, e2)
    STEP(3, e3)
    e0 = n0; e1 = n1; e2 = n2; e3 = n3;
  }

epi:
  {
    f32x2 o = unpackh(cbuf[role][fin][l]);
    *(f32x2*)(ws + (size_t)b * 512 + role * 128 + 2 * l) = o;
    if (l == 0) ewbuf[role * BATCH + b] = Ew;
  }
}

// ---------------------------------------------------------------------------
// Combine: total = (EwFL+EwFR)ln2 + log(sum_k WL*WR);
//          best  = (EwVL+EwVR)ln2 + log(max_k VL*VR).
// ---------------------------------------------------------------------------
__global__ __launch_bounds__(128, 1)
void crf_combine_kernel(const float* __restrict__ ws,
                        const int* __restrict__ ewbuf,
                        float* __restrict__ out)
{
  const int b = blockIdx.x, k = threadIdx.x;
  const float* base = ws + (size_t)b * 512;
  float t1 = base[k] * base[128 + k];
  float m1 = base[256 + k] * base[384 + k];
#pragma unroll
  for (int d = 1; d <= 32; d <<= 1) {
    t1 += __shfl_xor(t1, d);
    m1 = fmaxf(m1, __shfl_xor(m1, d));
  }
  __shared__ float rs[2], rm[2];
  const int lane = k & 63, wid = k >> 6;
  if (lane == 0) { rs[wid] = t1; rm[wid] = m1; }
  __syncthreads();
  if (k == 0) {
    const double LN2 = 0.6931471805599453;
    int EtF = ewbuf[b] + ewbuf[BATCH + b];
    int EtV = ewbuf[2 * BATCH + b] + ewbuf[3 * BATCH + b];
    out[1 + BATCH + b] =
        (float)((double)EtF * LN2 + (double)__logf(rs[0] + rs[1]));
    out[1 + 2 * BATCH + b] =
        (float)((double)EtV * LN2 + (double)__logf(fmaxf(rm[0], rm[1])));
  }
}

// ---------------------------------------------------------------------------
// loss = mean(total_score - real_path_score)
// ---------------------------------------------------------------------------
__global__ __launch_bounds__(256, 1)
void crf_loss_kernel(float* __restrict__ out)
{
  const int tid = threadIdx.x;
  float dft = out[1 + BATCH + tid] - out[1 + tid];
#pragma unroll
  for (int d = 1; d <= 32; d <<= 1) dft += __shfl_xor(dft, d);
  __shared__ float rs[4];
  const int lane = tid & 63, wid = tid >> 6;
  if (lane == 0) rs[wid] = dft;
  __syncthreads();
  if (tid == 0)
    out[0] = ((rs[0] + rs[1]) + (rs[2] + rs[3])) * (1.0f / BATCH);
}

extern "C" void kernel_launch(void* const* d_in, const int* in_sizes, int n_in,
                              void* d_out, int out_size, void* d_ws, size_t ws_size,
                              hipStream_t stream)
{
  const float* emis   = (const float*)d_in[0];
  const float* mask   = (const float*)d_in[1];
  const int*   tags   = (const int*)d_in[2];
  const float* trans  = (const float*)d_in[3];
  const float* startt = (const float*)d_in[4];
  const float* stopt  = (const float*)d_in[5];
  float* out = (float*)d_out;

  float* wsf   = (float*)d_ws;                 // 256 * 512 floats
  int*   ewbuf = (int*)(wsf + 512 * BATCH);    // 4 * 256 ints

  crf_chain_kernel<<<2 * BATCH, 256, 0, stream>>>(emis, mask, tags, trans,
                                                  startt, stopt, wsf, ewbuf, out);
  crf_combine_kernel<<<BATCH, 128, 0, stream>>>(wsf, ewbuf, out);
  crf_loss_kernel<<<1, 256, 0, stream>>>(out);
}

// Round 10
// 249.168 us; speedup vs baseline: 1.0166x; 1.0166x over previous
//
#include <hip/hip_runtime.h>
#include <math.h>

#define S_LEN 512
#define BATCH 256
#define NTAG  128
#define EMSTRIDE (BATCH * NTAG)  /* floats per time step */

typedef float f32x4 __attribute__((ext_vector_type(4)));
typedef float f32x2 __attribute__((ext_vector_type(2)));

// swizzled LDS float index: pad 8 floats after every 32 -> the 4 k-quarters'
// broadcast addresses land on disjoint bank quads (R4-proven, 0 conflicts).
__device__ __forceinline__ int swz(int k) { return k + ((k >> 5) << 3); }

__device__ __forceinline__ f32x2 lo2(f32x4 v){ f32x2 r; r[0]=v[0]; r[1]=v[1]; return r; }
__device__ __forceinline__ f32x2 hi2(f32x4 v){ f32x2 r; r[0]=v[2]; r[1]=v[3]; return r; }
__device__ __forceinline__ f32x2 pmax2(f32x2 a, f32x2 b){ f32x2 r; r[0]=fmaxf(a[0],b[0]); r[1]=fmaxf(a[1],b[1]); return r; }
__device__ __forceinline__ f32x2 fma2(f32x2 a, f32x2 b, f32x2 c){ f32x2 r; r[0]=__builtin_fmaf(a[0],b[0],c[0]); r[1]=__builtin_fmaf(a[1],b[1],c[1]); return r; }

// DPP quad-perm butterfly (intra-quad, VALU-speed, no LDS pipe)
#define DPP_XOR1(x) __int_as_float(__builtin_amdgcn_mov_dpp(__float_as_int(x), 0xB1, 0xF, 0xF, false))
#define DPP_XOR2(x) __int_as_float(__builtin_amdgcn_mov_dpp(__float_as_int(x), 0x4E, 0xF, 0xF, false))

// Raw barrier: drain LDS only (NOT vmcnt) so global prefetch stays in flight.
#define BAR() do {                                       \
    asm volatile("s_waitcnt lgkmcnt(0)" ::: "memory");   \
    __builtin_amdgcn_s_barrier();                        \
    __builtin_amdgcn_sched_barrier(0);                   \
  } while (0)

__device__ __forceinline__ int emt(bool isR, int len, int i) {
  int s = isR ? (len - 2 - i) : (1 + i);
  s = s < 0 ? 0 : s;
  return s > S_LEN - 1 ? S_LEN - 1 : s;
}

// ---------------------------------------------------------------------------
// Chain kernel, 256 threads (4 waves), grid = 4*128 + 256:
//   blk < 512: role = blk>>7 (0=FL,1=FR,2=VL,3=VR), pair = blk&127,
//              batches bA=pair, bB=pair+128 — TWO chains interleaved per
//              step, ONE barrier per pair-step (A's LDS latency hides under
//              B's compute and vice versa). Same role => shared E registers.
//   blk >= 512: gold-path block for b = blk-512.
// Thread map: g=tid>>2 owns rows {2g,2g+1}; h=tid&3 owns cols [32h,32h+32).
// E/T = 64 f32/thread (no spill). Meet at sm=(len-1)>>1 (left cnt=sm,
// right cnt=len-1-sm). Fwd in exp space w/ pow2 renorm every 4th step;
// viterbi in log space (exact). Identical math to R8 (absmax 0).
// ---------------------------------------------------------------------------
__global__ __launch_bounds__(256, 2)
void crf_chain_kernel(const float* __restrict__ emis,
                      const float* __restrict__ mask,
                      const int* __restrict__ tags,
                      const float* __restrict__ trans,
                      const float* __restrict__ startt,
                      const float* __restrict__ stopt,
                      float* __restrict__ ws,
                      int* __restrict__ ewbuf,
                      float* __restrict__ out)
{
  const int blk  = blockIdx.x;
  const int tid  = threadIdx.x;
  const int lane = tid & 63;
  const int wid  = tid >> 6;

  __shared__ __align__(16) float sA[2][160];
  __shared__ __align__(16) float sB[2][160];
  __shared__ float red[16];

  // ---------------- gold role ----------------
  if (blk >= 512) {
    const int b = blk - 512;
    float part = 0.f, lenp = 0.f;
#pragma unroll
    for (int rep = 0; rep < 2; ++rep) {
      int s = tid + rep * 256;
      float m  = mask[(size_t)s * BATCH + b];
      int  cur = tags[(size_t)s * BATCH + b];
      if (s == 0) {
        part += startt[cur] + emis[(size_t)b * NTAG + cur] * m;
      } else {
        int prev = tags[(size_t)(s - 1) * BATCH + b];
        part += m * (trans[(size_t)prev * NTAG + cur] +
                     emis[((size_t)s * BATCH + b) * NTAG + cur]);
      }
      lenp += m;
    }
#pragma unroll
    for (int d = 1; d <= 32; d <<= 1) {
      part += __shfl_xor(part, d);
      lenp += __shfl_xor(lenp, d);
    }
    if (lane == 0) { red[wid] = part; red[8 + wid] = lenp; }
    __syncthreads();
    if (tid == 0) {
      float rps = (red[0] + red[1]) + (red[2] + red[3]);
      float lf  = (red[8] + red[9]) + (red[10] + red[11]);
      int len = (int)(lf + 0.5f);
      int pf  = tags[(size_t)(len - 1) * BATCH + b];
      out[1 + b] = rps + stopt[pf];
    }
    return;
  }

  const int  role = blk >> 7;
  const int  bA   = blk & 127;
  const int  bB   = bA + 128;
  const bool isR  = (role & 1) != 0;
  const bool isV  = (role >= 2);
  const int  h    = tid & 3;
  const int  g    = tid >> 2;      // rows 2g, 2g+1

  // ---- lengths of both batches (mask monotone) ----
  int lenA, lenB;
  {
    float ma = mask[(size_t)tid * BATCH + bA] +
               mask[(size_t)(tid + 256) * BATCH + bA];
    float mb = mask[(size_t)tid * BATCH + bB] +
               mask[(size_t)(tid + 256) * BATCH + bB];
#pragma unroll
    for (int d = 1; d <= 32; d <<= 1) {
      ma += __shfl_xor(ma, d);
      mb += __shfl_xor(mb, d);
    }
    if (lane == 0) { red[wid] = ma; red[8 + wid] = mb; }
    __syncthreads();
    float la = (red[0] + red[1]) + (red[2] + red[3]);
    float lb = (red[8] + red[9]) + (red[10] + red[11]);
    lenA = __builtin_amdgcn_readfirstlane((int)(la + 0.5f));
    lenB = __builtin_amdgcn_readfirstlane((int)(lb + 0.5f));
  }
  const int smA = (lenA - 1) >> 1, nstA = lenA - 1 - smA;
  const int smB = (lenB - 1) >> 1, nstB = lenB - 1 - smB;
  const int cntA = isR ? nstA : smA;
  const int cntB = isR ? nstB : smB;

  // ---- E/T: rows 2g,2g+1 x cols [32h,32h+32) in 64 f32 (as 32 f32x2) ----
  f32x2 M0[16], M1[16];
  if (!isR) {
    const float* r0 = trans + (size_t)(2 * g) * NTAG + 32 * h;
    const float* r1 = r0 + NTAG;
#pragma unroll
    for (int c = 0; c < 8; ++c) {
      f32x4 t0 = *(const f32x4*)(r0 + 4 * c);
      f32x4 t1 = *(const f32x4*)(r1 + 4 * c);
      M0[2*c] = lo2(t0); M0[2*c+1] = hi2(t0);
      M1[2*c] = lo2(t1); M1[2*c+1] = hi2(t1);
    }
  } else {
    const float* tc = trans + (size_t)(32 * h) * NTAG + 2 * g;
#pragma unroll
    for (int kk = 0; kk < 16; ++kk) {
      f32x2 p0 = *(const f32x2*)(tc + (size_t)(2 * kk) * NTAG);
      f32x2 p1 = *(const f32x2*)(tc + (size_t)(2 * kk + 1) * NTAG);
      f32x2 a, bb;
      a[0] = p0[0];  a[1] = p1[0];   // row 2g:   cols 2kk, 2kk+1
      bb[0] = p0[1]; bb[1] = p1[1];  // row 2g+1
      M0[kk] = a; M1[kk] = bb;
    }
  }
  if (!isV) {
#pragma unroll
    for (int c = 0; c < 16; ++c) {
      M0[c][0] = __expf(M0[c][0]); M0[c][1] = __expf(M0[c][1]);
      M1[c][0] = __expf(M1[c][0]); M1[c][1] = __expf(M1[c][1]);
    }
  }

  const float* ebA = emis + (size_t)bA * NTAG + 2 * g;
  const float* ebB = emis + (size_t)bB * NTAG + 2 * g;

  // ---- init states ----
  if (h == 0) {
    f32x2 s0A, s0B;
    if (!isR) {
      f32x2 st = *(const f32x2*)(startt + 2 * g);
      s0A = st + *(const f32x2*)ebA;
      s0B = st + *(const f32x2*)ebB;
    } else {
      f32x2 st = *(const f32x2*)(stopt + 2 * g);
      f32x2 eLA = {0.f, 0.f}, eLB = {0.f, 0.f};
      if (nstA > 0) eLA = *(const f32x2*)(ebA + (size_t)(lenA - 1) * EMSTRIDE);
      if (nstB > 0) eLB = *(const f32x2*)(ebB + (size_t)(lenB - 1) * EMSTRIDE);
      s0A = st + eLA;
      s0B = st + eLB;
    }
    if (!isV) {
      s0A[0] = __expf(s0A[0]); s0A[1] = __expf(s0A[1]);
      s0B[0] = __expf(s0B[0]); s0B[1] = __expf(s0B[1]);
    }
    *(f32x2*)&sA[0][swz(2 * g)] = s0A;
    *(f32x2*)&sB[0][swz(2 * g)] = s0B;
  }

  // ---- emission prefetch, both chains, depth 4 ----
  f32x2 eA0 = *(const f32x2*)(ebA + (size_t)emt(isR, lenA, 0) * EMSTRIDE);
  f32x2 eA1 = *(const f32x2*)(ebA + (size_t)emt(isR, lenA, 1) * EMSTRIDE);
  f32x2 eA2 = *(const f32x2*)(ebA + (size_t)emt(isR, lenA, 2) * EMSTRIDE);
  f32x2 eA3 = *(const f32x2*)(ebA + (size_t)emt(isR, lenA, 3) * EMSTRIDE);
  f32x2 eB0 = *(const f32x2*)(ebB + (size_t)emt(isR, lenB, 0) * EMSTRIDE);
  f32x2 eB1 = *(const f32x2*)(ebB + (size_t)emt(isR, lenB, 1) * EMSTRIDE);
  f32x2 eB2 = *(const f32x2*)(ebB + (size_t)emt(isR, lenB, 2) * EMSTRIDE);
  f32x2 eB3 = *(const f32x2*)(ebB + (size_t)emt(isR, lenB, 3) * EMSTRIDE);

  int EwA = 0, EwB = 0;
  __syncthreads();

#define FSTEP1(U, SB, EV, RN, EW, ISLAST)                                     \
  {                                                                           \
    const f32x4* wr_ = (const f32x4*)SB[(U) & 1] + 10 * h;                    \
    f32x2 a0_ = {0.f,0.f}, a1_ = {0.f,0.f}, r2_ = {0.f,0.f};                  \
    _Pragma("unroll")                                                         \
    for (int c = 0; c < 8; ++c) {                                             \
      f32x4 w_ = wr_[c];                                                      \
      f32x2 wl_ = lo2(w_), wh_ = hi2(w_);                                     \
      a0_ = fma2(M0[2*c], wl_, a0_); a0_ = fma2(M0[2*c+1], wh_, a0_);         \
      a1_ = fma2(M1[2*c], wl_, a1_); a1_ = fma2(M1[2*c+1], wh_, a1_);         \
      if (RN) r2_ = pmax2(r2_, pmax2(wl_, wh_));                              \
    }                                                                         \
    float s0_ = a0_[0] + a0_[1], s1_ = a1_[0] + a1_[1];                       \
    s0_ += DPP_XOR1(s0_); s0_ += DPP_XOR2(s0_);                               \
    s1_ += DPP_XOR1(s1_); s1_ += DPP_XOR2(s1_);                               \
    float ex0_ = 1.f, ex1_ = 1.f;                                             \
    if (!(ISLAST)) { ex0_ = __expf((EV)[0]); ex1_ = __expf((EV)[1]); }        \
    float u0_, u1_;                                                           \
    if (RN) {                                                                 \
      float rw_ = fmaxf(r2_[0], r2_[1]);                                      \
      rw_ = fmaxf(rw_, DPP_XOR1(rw_)); rw_ = fmaxf(rw_, DPP_XOR2(rw_));       \
      int ew_ = (int)((__float_as_uint(rw_) >> 23) & 0xFF) - 126;             \
      EW += ew_;                                                              \
      float sc_ = __uint_as_float((unsigned)(127 - ew_) << 23);               \
      u0_ = ex0_ * s0_ * sc_; u1_ = ex1_ * s1_ * sc_;                         \
    } else {                                                                  \
      u0_ = ex0_ * s0_; u1_ = ex1_ * s1_;                                     \
    }                                                                         \
    if (h == 0) {                                                             \
      f32x2 u_; u_[0] = u0_; u_[1] = u1_;                                     \
      *(f32x2*)&SB[((U) + 1) & 1][swz(2 * g)] = u_;                           \
    }                                                                         \
  }

#define VSTEP1(U, SB, EV, ISLAST)                                             \
  {                                                                           \
    const f32x4* vr_ = (const f32x4*)SB[(U) & 1] + 10 * h;                    \
    f32x2 m0_ = {-3.0e38f,-3.0e38f}, m1_ = {-3.0e38f,-3.0e38f};               \
    _Pragma("unroll")                                                         \
    for (int c = 0; c < 8; ++c) {                                             \
      f32x4 v_ = vr_[c];                                                      \
      f32x2 vl_ = lo2(v_), vh_ = hi2(v_);                                     \
      m0_ = pmax2(m0_, pmax2(vl_ + M0[2*c], vh_ + M0[2*c+1]));                \
      m1_ = pmax2(m1_, pmax2(vl_ + M1[2*c], vh_ + M1[2*c+1]));                \
    }                                                                         \
    float s0_ = fmaxf(m0_[0], m0_[1]), s1_ = fmaxf(m1_[0], m1_[1]);           \
    s0_ = fmaxf(s0_, DPP_XOR1(s0_)); s0_ = fmaxf(s0_, DPP_XOR2(s0_));         \
    s1_ = fmaxf(s1_, DPP_XOR1(s1_)); s1_ = fmaxf(s1_, DPP_XOR2(s1_));         \
    if (h == 0) {                                                             \
      f32x2 u_;                                                               \
      u_[0] = (ISLAST) ? s0_ : s0_ + (EV)[0];                                 \
      u_[1] = (ISLAST) ? s1_ : s1_ + (EV)[1];                                 \
      *(f32x2*)&SB[((U) + 1) & 1][swz(2 * g)] = u_;                           \
    }                                                                         \
  }

#define SUB(U, EVA, EVB, RN)                                                  \
  {                                                                           \
    const int i_ = gb + (U);                                                  \
    if (i_ >= cntA && i_ >= cntB) goto epi;                                   \
    if (!isV) {                                                               \
      if (i_ < cntA) FSTEP1(U, sA, EVA, RN, EwA, isR && (i_ == cntA - 1))     \
      if (i_ < cntB) FSTEP1(U, sB, EVB, RN, EwB, isR && (i_ == cntB - 1))     \
    } else {                                                                  \
      if (i_ < cntA) VSTEP1(U, sA, EVA, isR && (i_ == cntA - 1))              \
      if (i_ < cntB) VSTEP1(U, sB, EVB, isR && (i_ == cntB - 1))              \
    }                                                                         \
    BAR();                                                                    \
  }

  for (int gb = 0; gb < 256; gb += 4) {
    f32x2 nA0 = *(const f32x2*)(ebA + (size_t)emt(isR, lenA, gb + 4) * EMSTRIDE);
    f32x2 nA1 = *(const f32x2*)(ebA + (size_t)emt(isR, lenA, gb + 5) * EMSTRIDE);
    f32x2 nA2 = *(const f32x2*)(ebA + (size_t)emt(isR, lenA, gb + 6) * EMSTRIDE);
    f32x2 nA3 = *(const f32x2*)(ebA + (size_t)emt(isR, lenA, gb + 7) * EMSTRIDE);
    f32x2 nB0 = *(const f32x2*)(ebB + (size_t)emt(isR, lenB, gb + 4) * EMSTRIDE);
    f32x2 nB1 = *(const f32x2*)(ebB + (size_t)emt(isR, lenB, gb + 5) * EMSTRIDE);
    f32x2 nB2 = *(const f32x2*)(ebB + (size_t)emt(isR, lenB, gb + 6) * EMSTRIDE);
    f32x2 nB3 = *(const f32x2*)(ebB + (size_t)emt(isR, lenB, gb + 7) * EMSTRIDE);

    SUB(0, eA0, eB0, 0)
    SUB(1, eA1, eB1, 0)
    SUB(2, eA2, eB2, 0)
    SUB(3, eA3, eB3, 1)   // fwd renorm every 4th step (growth < 2^90, safe)

    eA0 = nA0; eA1 = nA1; eA2 = nA2; eA3 = nA3;
    eB0 = nB0; eB1 = nB1; eB2 = nB2; eB3 = nB3;
  }

epi: ;
  {
    if (h == 0) {
      f32x2 oA = *(const f32x2*)&sA[cntA & 1][swz(2 * g)];
      f32x2 oB = *(const f32x2*)&sB[cntB & 1][swz(2 * g)];
      *(f32x2*)(ws + (size_t)bA * 512 + role * 128 + 2 * g) = oA;
      *(f32x2*)(ws + (size_t)bB * 512 + role * 128 + 2 * g) = oB;
    }
    if (tid == 0 && !isV) {
      ewbuf[role * BATCH + bA] = EwA;
      ewbuf[role * BATCH + bB] = EwB;
    }
  }
}

// ---------------------------------------------------------------------------
// Combine: total = (EwFL+EwFR)ln2 + log(sum_k WL*WR); best = max_k(VL+VR).
// ---------------------------------------------------------------------------
__global__ __launch_bounds__(128, 1)
void crf_combine_kernel(const float* __restrict__ ws,
                        const int* __restrict__ ewbuf,
                        float* __restrict__ out)
{
  const int b = blockIdx.x, k = threadIdx.x;
  const float* base = ws + (size_t)b * 512;
  float t1 = base[k] * base[128 + k];
  float m1 = base[256 + k] + base[384 + k];
#pragma unroll
  for (int d = 1; d <= 32; d <<= 1) {
    t1 += __shfl_xor(t1, d);
    m1 = fmaxf(m1, __shfl_xor(m1, d));
  }
  __shared__ float rs[2], rm[2];
  const int lane = k & 63, wid = k >> 6;
  if (lane == 0) { rs[wid] = t1; rm[wid] = m1; }
  __syncthreads();
  if (k == 0) {
    const double LN2 = 0.6931471805599453;
    int Et = ewbuf[b] + ewbuf[BATCH + b];
    out[1 + BATCH + b]     = (float)((double)Et * LN2 + (double)__logf(rs[0] + rs[1]));
    out[1 + 2 * BATCH + b] = fmaxf(rm[0], rm[1]);
  }
}

// ---------------------------------------------------------------------------
// loss = mean(total_score - real_path_score)
// ---------------------------------------------------------------------------
__global__ __launch_bounds__(256, 1)
void crf_loss_kernel(float* __restrict__ out)
{
  const int tid = threadIdx.x;
  float dft = out[1 + BATCH + tid] - out[1 + tid];
#pragma unroll
  for (int d = 1; d <= 32; d <<= 1) dft += __shfl_xor(dft, d);
  __shared__ float rs[4];
  const int lane = tid & 63, wid = tid >> 6;
  if (lane == 0) rs[wid] = dft;
  __syncthreads();
  if (tid == 0)
    out[0] = ((rs[0] + rs[1]) + (rs[2] + rs[3])) * (1.0f / BATCH);
}

extern "C" void kernel_launch(void* const* d_in, const int* in_sizes, int n_in,
                              void* d_out, int out_size, void* d_ws, size_t ws_size,
                              hipStream_t stream)
{
  const float* emis   = (const float*)d_in[0];
  const float* mask   = (const float*)d_in[1];
  const int*   tags   = (const int*)d_in[2];
  const float* trans  = (const float*)d_in[3];
  const float* startt = (const float*)d_in[4];
  const float* stopt  = (const float*)d_in[5];
  float* out = (float*)d_out;

  float* wsf   = (float*)d_ws;                 // 256 * 512 floats
  int*   ewbuf = (int*)(wsf + 512 * BATCH);    // 2 * 256 ints

  crf_chain_kernel<<<768, 256, 0, stream>>>(emis, mask, tags, trans,
                                            startt, stopt, wsf, ewbuf, out);
  crf_combine_kernel<<<BATCH, 128, 0, stream>>>(wsf, ewbuf, out);
  crf_loss_kernel<<<1, 256, 0, stream>>>(out);
}